// Round 8
// baseline (123.598 us; speedup 1.0000x reference)
//
#include <hip/hip_runtime.h>
#include <hip/hip_bf16.h>
#include <stdint.h>

#define B_ 16
#define N_ 512
#define E_ 8192
#define D_ 256
#define NBUCKET (B_ * N_)          // bucket per (batch, dst node) = 8192
#define CAP 64                     // records per bucket (mean 8, 11-sigma safe)
#define SCORE_BLOCKS 4096

// ---- workspace layout (float offsets) ----
constexpr int OFF_VE  = 16;
constexpr int OFF_TN  = OFF_VE + D_;
constexpr int OFF_S1P = OFF_TN + B_*N_*D_;        // 4 x NBUCKET partials
constexpr int OFF_S2P = OFF_S1P + 4*NBUCKET;
constexpr int OFF_SC  = OFF_S2P + 4*NBUCKET;
constexpr int OFF_SM  = OFF_SC + B_*E_;           // 32 floats: per-batch M, 1/S
constexpr int OFF_CNT = OFF_SM + 32;              // 8192 ints
constexpr int OFF_REC = OFF_CNT + NBUCKET;        // int x NBUCKET*CAP (2 MB)

__device__ __forceinline__ float bf2f(uint16_t u) {
    union { uint32_t i; float f; } v; v.i = ((uint32_t)u) << 16; return v.f;
}

__device__ __forceinline__ float loadF(const void* p, int i, int isBF) {
    if (isBF) return __bfloat162float(((const __hip_bfloat16*)p)[i]);
    return ((const float*)p)[i];
}

__device__ __forceinline__ float4 loadF4(const void* p, int i, int isBF) {
    if (isBF) {
        ushort4 v = *(const ushort4*)((const uint16_t*)p + i);
        return make_float4(bf2f(v.x), bf2f(v.y), bf2f(v.z), bf2f(v.w));
    }
    return *(const float4*)((const float*)p + i);
}

// mask layouts: 0=u8/bool, 1=int32, 2=bf16, 3=f32
__device__ __forceinline__ bool readMask(const void* p, int i, int ml) {
    if (ml == 0) return ((const uint8_t*)p)[i] != 0;
    if (ml == 1) return ((const int*)p)[i] != 0;
    if (ml == 2) return (((const uint16_t*)p)[i] & 0x7FFFu) != 0;
    return (((const uint32_t*)p)[i] & 0x7FFFFFFFu) != 0;
}

// Inline dtype/mask-layout detection: pure function of fixed input words
// (wave-uniform broadcast loads, L2-hot). obj ~ N(0,1): if f32, the low
// halfwords seen as bf16 have random exponents ("insane"); if bf16, none.
__device__ __forceinline__ void detect(const void* obj, const void* emask,
                                       int& isBF, int& ml) {
    const uint32_t* ow = (const uint32_t*)obj;
    int insane = 0;
    #pragma unroll
    for (int i = 0; i < 32; ++i) {
        uint32_t x = ow[i];
        uint32_t lo = x & 0xFFFFu, hi = x >> 16;
        uint32_t el = (lo >> 7) & 0xFFu, eh = (hi >> 7) & 0xFFu;
        if ((lo & 0x7FFFu) && (el < 107u || el > 147u)) insane++;
        if ((hi & 0x7FFFu) && (eh < 107u || eh > 147u)) insane++;
    }
    isBF = (insane >= 8) ? 0 : 1;   // f32 -> ~27/64 insane; bf16 -> ~0
    const uint32_t* ew = (const uint32_t*)emask;
    bool i32ok = true, f32ok = true, bfok = true;
    #pragma unroll
    for (int i = 0; i < 16; ++i) {
        uint32_t x = ew[i];
        if (x > 1u) i32ok = false;
        if (x != 0u && x != 0x3F800000u) f32ok = false;
        uint32_t lo = x & 0xFFFFu, hi = x >> 16;
        if (!((lo == 0u || lo == 0x3F80u) && (hi == 0u || hi == 0x3F80u))) bfok = false;
    }
    ml = i32ok ? 1 : (f32ok ? 3 : (bfok ? 2 : 0));
}

// ---- K1: tn = obj @ w_node^T (tiled f32 SGEMM, NT) + s1/s2 partials
//          + block 0: v_edge  + last block: zero CNT ----
__global__ __launch_bounds__(256) void k_nodefc(const void* obj, const void* wn,
                                                const void* we, const void* wa,
                                                const void* emask, float* ws) {
    int isBF, ml;
    detect(obj, emask, isBF, ml);
    (void)ml;
    __shared__ float As[32][68];
    __shared__ float Bs[32][68];
    float* tn = ws + OFF_TN;
    int t = threadIdx.x;
    int tx = t & 15, ty = t >> 4;
    int bm = blockIdx.x >> 2, bn = blockIdx.x & 3;
    int row0 = bm * 64, col0 = bn * 64;
    int sr = t >> 2;
    int sk = (t & 3) * 8;
    float acc[4][4] = {};
    for (int kt = 0; kt < 8; ++kt) {
        int k0 = kt * 32;
        __syncthreads();
        float4 a0 = loadF4(obj, (row0 + sr) * D_ + k0 + sk, isBF);
        float4 a1 = loadF4(obj, (row0 + sr) * D_ + k0 + sk + 4, isBF);
        float4 b0 = loadF4(wn, (col0 + sr) * D_ + k0 + sk, isBF);
        float4 b1 = loadF4(wn, (col0 + sr) * D_ + k0 + sk + 4, isBF);
        As[sk+0][sr] = a0.x; As[sk+1][sr] = a0.y; As[sk+2][sr] = a0.z; As[sk+3][sr] = a0.w;
        As[sk+4][sr] = a1.x; As[sk+5][sr] = a1.y; As[sk+6][sr] = a1.z; As[sk+7][sr] = a1.w;
        Bs[sk+0][sr] = b0.x; Bs[sk+1][sr] = b0.y; Bs[sk+2][sr] = b0.z; Bs[sk+3][sr] = b0.w;
        Bs[sk+4][sr] = b1.x; Bs[sk+5][sr] = b1.y; Bs[sk+6][sr] = b1.z; Bs[sk+7][sr] = b1.w;
        __syncthreads();
        #pragma unroll
        for (int k = 0; k < 32; ++k) {
            float4 av = *(const float4*)&As[k][ty * 4];
            float4 bv = *(const float4*)&Bs[k][tx * 4];
            acc[0][0] += av.x * bv.x; acc[0][1] += av.x * bv.y;
            acc[0][2] += av.x * bv.z; acc[0][3] += av.x * bv.w;
            acc[1][0] += av.y * bv.x; acc[1][1] += av.y * bv.y;
            acc[1][2] += av.y * bv.z; acc[1][3] += av.y * bv.w;
            acc[2][0] += av.z * bv.x; acc[2][1] += av.z * bv.y;
            acc[2][2] += av.z * bv.z; acc[2][3] += av.z * bv.w;
            acc[3][0] += av.w * bv.x; acc[3][1] += av.w * bv.y;
            acc[3][2] += av.w * bv.z; acc[3][3] += av.w * bv.w;
        }
    }
    #pragma unroll
    for (int rr = 0; rr < 4; ++rr) {
        float4 o = make_float4(acc[rr][0], acc[rr][1], acc[rr][2], acc[rr][3]);
        *(float4*)&tn[(size_t)(row0 + ty * 4 + rr) * D_ + col0 + tx * 4] = o;
    }
    // s1/s2 partial dots over this block's 64 cols -> single-writer slot [bn]
    float w1v[4], w2v[4];
    #pragma unroll
    for (int c = 0; c < 4; ++c) {
        w1v[c] = loadF(wa, col0 + tx * 4 + c, isBF);
        w2v[c] = loadF(wa, D_ + col0 + tx * 4 + c, isBF);
    }
    #pragma unroll
    for (int rr = 0; rr < 4; ++rr) {
        float p1 = acc[rr][0]*w1v[0] + acc[rr][1]*w1v[1] + acc[rr][2]*w1v[2] + acc[rr][3]*w1v[3];
        float p2 = acc[rr][0]*w2v[0] + acc[rr][1]*w2v[1] + acc[rr][2]*w2v[2] + acc[rr][3]*w2v[3];
        #pragma unroll
        for (int o = 1; o < 16; o <<= 1) {
            p1 += __shfl_xor(p1, o);
            p2 += __shfl_xor(p2, o);
        }
        if (tx == 0) {
            ws[OFF_S1P + bn * NBUCKET + row0 + ty * 4 + rr] = p1;
            ws[OFF_S2P + bn * NBUCKET + row0 + ty * 4 + rr] = p2;
        }
    }
    // block 0: v_edge[t] = sum_d wa3[d] * w_edge[d][t]
    if (blockIdx.x == 0) {
        float a = 0.f;
        for (int d = 0; d < D_; ++d)
            a += loadF(wa, 513 + d, isBF) * loadF(we, d * D_ + t, isBF);
        ws[OFF_VE + t] = a;
    }
    // last block: zero bucket counters for k_scores
    if (blockIdx.x == gridDim.x - 1) {
        for (int i = t; i < NBUCKET; i += 256) ((int*)ws)[OFF_CNT + i] = 0;
    }
}

// ---- K2: edge scores (wave per edge, grid-stride) + bucket fill.
//          Masked edges skip the pred row read entirely (halves pred traffic). ----
__global__ __launch_bounds__(256) void k_scores(const void* obj, const void* pred,
                                                const int2* rel, const void* emask,
                                                const void* sim, const void* wa,
                                                float* ws) {
    int isBF, ml;
    detect(obj, emask, isBF, ml);
    int gid = blockIdx.x * 256 + threadIdx.x;
    int wv = gid >> 6, lane = gid & 63;
    float4 ve4 = *(const float4*)(ws + OFF_VE + lane * 4);
    float simc = loadF(wa, 512, isBF);
    int stride = SCORE_BLOCKS * 4;          // waves in grid
    for (int gw = wv; gw < B_ * E_; gw += stride) {
        bool m = readMask(emask, gw, ml);   // wave-uniform
        if (!m) {
            if (lane == 0) ws[OFF_SC + gw] = -1e9f;
            continue;
        }
        int b = gw >> 13;
        float dot;
        if (isBF) {
            ushort4 v = *(const ushort4*)((const uint16_t*)pred + (size_t)gw * D_ + lane * 4);
            dot = bf2f(v.x)*ve4.x + bf2f(v.y)*ve4.y + bf2f(v.z)*ve4.z + bf2f(v.w)*ve4.w;
        } else {
            float4 v = *(const float4*)((const float*)pred + (size_t)gw * D_ + lane * 4);
            dot = v.x*ve4.x + v.y*ve4.y + v.z*ve4.z + v.w*ve4.w;
        }
        #pragma unroll
        for (int off = 32; off > 0; off >>= 1) dot += __shfl_xor(dot, off);
        if (lane == 0) {
            int2 sd = rel[gw];
            int ib = b * N_;
            float s1 = ws[OFF_S1P + ib + sd.x] + ws[OFF_S1P + NBUCKET + ib + sd.x]
                     + ws[OFF_S1P + 2*NBUCKET + ib + sd.x] + ws[OFF_S1P + 3*NBUCKET + ib + sd.x];
            float s2 = ws[OFF_S2P + ib + sd.y] + ws[OFF_S2P + NBUCKET + ib + sd.y]
                     + ws[OFF_S2P + 2*NBUCKET + ib + sd.y] + ws[OFF_S2P + 3*NBUCKET + ib + sd.y];
            float s = dot + s1 + s2 + loadF(sim, gw, isBF) * simc;
            s = (s > 0.f) ? s : 0.01f * s;             // leaky_relu
            ws[OFF_SC + gw] = s;
            int bucket = ib + sd.y;
            int slot = atomicAdd((int*)ws + OFF_CNT + bucket, 1);
            if (slot < CAP)
                ((int*)ws)[OFF_REC + bucket * CAP + slot] = sd.x | ((gw & (E_ - 1)) << 16);
        }
    }
}

// ---- K3: per-batch softmax stats (M, 1/S) ----
__global__ __launch_bounds__(1024) void k_softmax(float* ws) {
    __shared__ float part[16];
    int b = blockIdx.x, t = threadIdx.x, w = t >> 6, lane = t & 63;
    const float* sc = ws + OFF_SC + b * E_;
    float loc[8];
    float mx = -3e38f;
    #pragma unroll
    for (int i = 0; i < 8; ++i) { loc[i] = sc[t + i * 1024]; mx = fmaxf(mx, loc[i]); }
    #pragma unroll
    for (int off = 32; off > 0; off >>= 1) mx = fmaxf(mx, __shfl_xor(mx, off));
    if (lane == 0) part[w] = mx;
    __syncthreads();
    float M = part[0];
    #pragma unroll
    for (int k = 1; k < 16; ++k) M = fmaxf(M, part[k]);
    float sum = 0.f;
    #pragma unroll
    for (int i = 0; i < 8; ++i) sum += __expf(loc[i] - M);
    #pragma unroll
    for (int off = 32; off > 0; off >>= 1) sum += __shfl_xor(sum, off);
    __syncthreads();
    if (lane == 0) part[w] = sum;
    __syncthreads();
    if (t == 0) {
        float S = 0.f;
        #pragma unroll
        for (int k = 0; k < 16; ++k) S += part[k];
        ws[OFF_SM + b * 2]     = M;
        ws[OFF_SM + b * 2 + 1] = 1.f / S;
    }
}

// ---- K4: one WAVE per (batch,node): register accum + mask + LayerNorm ----
__global__ __launch_bounds__(256) void k_scatter_ln(const void* obj, const void* emask,
                                                    const void* nmask, const void* gam,
                                                    const void* bet, const float* wsc,
                                                    void* out) {
    const float* ws = wsc;
    int isBF, ml;
    detect(obj, emask, isBF, ml);
    int t = threadIdx.x, w = t >> 6, lane = t & 63;
    int ng = blockIdx.x * 4 + w;           // (batch,node) bucket, 0..8191
    int b = ng >> 9;
    int cnt = ((const int*)ws)[OFF_CNT + ng];
    if (cnt > CAP) cnt = CAP;
    const int* rec = (const int*)ws + OFF_REC + ng * CAP;
    const float* tn  = ws + OFF_TN + (size_t)b * N_ * D_;
    const float* sc  = ws + OFF_SC + b * E_;
    float M    = ws[OFF_SM + b * 2];
    float invS = ws[OFF_SM + b * 2 + 1];
    float v0 = 0.f, v1 = 0.f, v2 = 0.f, v3 = 0.f;
    for (int i = 0; i < cnt; ++i) {
        int rc = rec[i];
        int src = rc & 0xFFFF;
        float wv = __expf(sc[((unsigned)rc) >> 16] - M) * invS;
        const float* s = tn + (size_t)src * D_;
        v0 += wv * s[lane];
        v1 += wv * s[lane + 64];
        v2 += wv * s[lane + 128];
        v3 += wv * s[lane + 192];
    }
    float mk = readMask(nmask, ng, ml) ? 1.f : 0.f;
    v0 *= mk; v1 *= mk; v2 *= mk; v3 *= mk;
    float sum = v0 + v1 + v2 + v3;
    float sq  = v0*v0 + v1*v1 + v2*v2 + v3*v3;
    #pragma unroll
    for (int o = 32; o > 0; o >>= 1) {
        sum += __shfl_xor(sum, o);
        sq  += __shfl_xor(sq, o);
    }
    float mu  = sum * (1.f / 256.f);
    float var = fmaxf(sq * (1.f / 256.f) - mu * mu, 0.f);
    float rs  = rsqrtf(var + 1e-5f);
    size_t ro = (size_t)ng * D_;
    float g0 = loadF(gam, lane,       isBF), b0v = loadF(bet, lane,       isBF);
    float g1 = loadF(gam, lane + 64,  isBF), b1v = loadF(bet, lane + 64,  isBF);
    float g2 = loadF(gam, lane + 128, isBF), b2v = loadF(bet, lane + 128, isBF);
    float g3 = loadF(gam, lane + 192, isBF), b3v = loadF(bet, lane + 192, isBF);
    float r0 = (v0 - mu) * rs * g0 + b0v;
    float r1 = (v1 - mu) * rs * g1 + b1v;
    float r2 = (v2 - mu) * rs * g2 + b2v;
    float r3 = (v3 - mu) * rs * g3 + b3v;
    if (isBF) {
        __hip_bfloat16* o = (__hip_bfloat16*)out + ro;
        o[lane]       = __float2bfloat16(r0);
        o[lane + 64]  = __float2bfloat16(r1);
        o[lane + 128] = __float2bfloat16(r2);
        o[lane + 192] = __float2bfloat16(r3);
    } else {
        float* o = (float*)out + ro;
        o[lane] = r0; o[lane + 64] = r1; o[lane + 128] = r2; o[lane + 192] = r3;
    }
}

extern "C" void kernel_launch(void* const* d_in, const int* in_sizes, int n_in,
                              void* d_out, int out_size, void* d_ws, size_t ws_size,
                              hipStream_t stream) {
    (void)in_sizes; (void)n_in; (void)out_size; (void)ws_size;
    const void* obj   = d_in[0];
    const void* pred  = d_in[1];
    const int2* rel   = (const int2*)d_in[2];
    const void* sim   = d_in[3];
    const void* nmask = d_in[4];
    const void* emask = d_in[5];
    const void* wn    = d_in[6];
    const void* we    = d_in[7];
    const void* wa    = d_in[8];
    const void* gam   = d_in[9];
    const void* bet   = d_in[10];
    float* ws = (float*)d_ws;

    k_nodefc<<<512, 256, 0, stream>>>(obj, wn, we, wa, emask, ws);
    k_scores<<<SCORE_BLOCKS, 256, 0, stream>>>(obj, pred, rel, emask, sim, wa, ws);
    k_softmax<<<16, 1024, 0, stream>>>(ws);
    k_scatter_ln<<<NBUCKET / 4, 256, 0, stream>>>(obj, emask, nmask, gam, bet, ws, d_out);
}

// Round 9
// 93.646 us; speedup vs baseline: 1.3198x; 1.3198x over previous
//
#include <hip/hip_runtime.h>
#include <hip/hip_bf16.h>
#include <stdint.h>

#define B_ 16
#define N_ 512
#define E_ 8192
#define D_ 256
#define NBUCKET (B_ * N_)          // bucket per (batch, dst node) = 8192
#define CAP 64                     // records per bucket (mean 8, 11-sigma safe)

// ---- workspace layout (float offsets) ----
constexpr int OFF_WN  = 16;                       // flags live in ws[0..1] (as int)
constexpr int OFF_WE  = OFF_WN + D_*D_;
constexpr int OFF_WA  = OFF_WE + D_*D_;           // 769 used, padded 1024
constexpr int OFF_GAM = OFF_WA + 1024;
constexpr int OFF_BET = OFF_GAM + D_;
constexpr int OFF_TN  = OFF_BET + D_;
constexpr int OFF_VE  = OFF_TN + B_*N_*D_;
constexpr int OFF_S1  = OFF_VE + D_;
constexpr int OFF_S2  = OFF_S1 + NBUCKET;
constexpr int OFF_SC  = OFF_S2 + NBUCKET;
constexpr int OFF_SM  = OFF_SC + B_*E_;           // 32 floats: per-batch M, 1/S
constexpr int OFF_CNT = OFF_SM + 32;              // 8192 ints
constexpr int OFF_REC = OFF_CNT + NBUCKET;        // int x NBUCKET*CAP (2 MB)
constexpr int CONV_TOTAL = D_*D_ + D_*D_ + 769 + D_ + D_;
constexpr int ZERO_TOTAL = NBUCKET + NBUCKET + NBUCKET + D_;  // CNT,S1,S2,VE

__device__ __forceinline__ float bf2f(uint16_t u) {
    union { uint32_t i; float f; } v; v.i = ((uint32_t)u) << 16; return v.f;
}

__device__ __forceinline__ float loadF(const void* p, int i, int isBF) {
    if (isBF) return __bfloat162float(((const __hip_bfloat16*)p)[i]);
    return ((const float*)p)[i];
}

__device__ __forceinline__ float4 loadF4(const void* p, int i, int isBF) {
    if (isBF) {
        ushort4 v = *(const ushort4*)((const uint16_t*)p + i);
        return make_float4(bf2f(v.x), bf2f(v.y), bf2f(v.z), bf2f(v.w));
    }
    return *(const float4*)((const float*)p + i);
}

// mask layouts: 0=u8/bool, 1=int32, 2=bf16, 3=f32
__device__ __forceinline__ bool readMask(const void* p, int i, int ml) {
    if (ml == 0) return ((const uint8_t*)p)[i] != 0;
    if (ml == 1) return ((const int*)p)[i] != 0;
    if (ml == 2) return (((const uint16_t*)p)[i] & 0x7FFFu) != 0;
    return (((const uint32_t*)p)[i] & 0x7FFFFFFFu) != 0;
}

// Inline dtype/mask-layout detection: pure function of fixed input words
// (wave-uniform broadcast loads, L2-hot after first wave).
__device__ __forceinline__ void detect(const void* obj, const void* emask,
                                       int& isBF, int& ml) {
    const uint32_t* ow = (const uint32_t*)obj;
    int insane = 0;
    #pragma unroll
    for (int i = 0; i < 32; ++i) {
        uint32_t x = ow[i];
        uint32_t lo = x & 0xFFFFu, hi = x >> 16;
        uint32_t el = (lo >> 7) & 0xFFu, eh = (hi >> 7) & 0xFFu;
        if ((lo & 0x7FFFu) && (el < 107u || el > 147u)) insane++;
        if ((hi & 0x7FFFu) && (eh < 107u || eh > 147u)) insane++;
    }
    isBF = (insane >= 8) ? 0 : 1;   // f32 -> ~27/64 insane; bf16 -> ~0
    const uint32_t* ew = (const uint32_t*)emask;
    bool i32ok = true, f32ok = true, bfok = true;
    #pragma unroll
    for (int i = 0; i < 16; ++i) {
        uint32_t x = ew[i];
        if (x > 1u) i32ok = false;
        if (x != 0u && x != 0x3F800000u) f32ok = false;
        uint32_t lo = x & 0xFFFFu, hi = x >> 16;
        if (!((lo == 0u || lo == 0x3F80u) && (hi == 0u || hi == 0x3F80u))) bfok = false;
    }
    ml = i32ok ? 1 : (f32ok ? 3 : (bfok ? 2 : 0));
}

// ---- K1: inline-detect + convert params to f32 scratch + zero CNT/S1/S2/VE
//          + publish flags for downstream kernels ----
__global__ void k_convert(const void* obj, const void* emask,
                          const void* wn, const void* we, const void* wa,
                          const void* gam, const void* bet, float* ws) {
    int isBF, ml;
    detect(obj, emask, isBF, ml);
    int stride = gridDim.x * blockDim.x;
    int gid = blockIdx.x * blockDim.x + threadIdx.x;
    if (gid == 0) { ((int*)ws)[0] = isBF; ((int*)ws)[1] = ml; }
    for (int i = gid; i < CONV_TOTAL; i += stride) {
        int j = i;
        if (j < D_*D_)    { ws[OFF_WN + j]  = loadF(wn, j, isBF); continue; }
        j -= D_*D_;
        if (j < D_*D_)    { ws[OFF_WE + j]  = loadF(we, j, isBF); continue; }
        j -= D_*D_;
        if (j < 769)      { ws[OFF_WA + j]  = loadF(wa, j, isBF); continue; }
        j -= 769;
        if (j < D_)       { ws[OFF_GAM + j] = loadF(gam, j, isBF); continue; }
        j -= D_;
        ws[OFF_BET + j] = loadF(bet, j, isBF);
    }
    for (int i = gid; i < ZERO_TOTAL; i += stride) {
        int j = i;
        if (j < NBUCKET) { ((int*)ws)[OFF_CNT + j] = 0; continue; }
        j -= NBUCKET;
        if (j < NBUCKET) { ws[OFF_S1 + j] = 0.f; continue; }
        j -= NBUCKET;
        if (j < NBUCKET) { ws[OFF_S2 + j] = 0.f; continue; }
        j -= NBUCKET;
        ws[OFF_VE + j] = 0.f;
    }
}

// ---- K1b: v_edge[k] += partial over 8 d-rows (32 blocks, parallel shape) ----
__global__ __launch_bounds__(256) void k_vedge(float* ws) {
    int t = threadIdx.x;
    int d0 = blockIdx.x * 8;
    const float* we  = ws + OFF_WE;
    const float* wa3 = ws + OFF_WA + 513;
    float a = 0.f;
    #pragma unroll
    for (int i = 0; i < 8; ++i) {
        int d = d0 + i;
        a += wa3[d] * we[d * D_ + t];
    }
    atomicAdd(&ws[OFF_VE + t], a);
}

// ---- K2: tn = obj @ w_node^T — tiled f32 SGEMM (NT) + fused s1/s2 partial dots ----
__global__ __launch_bounds__(256) void k_nodefc(const void* obj, float* ws) {
    int isBF = ((const int*)ws)[0];
    __shared__ float As[32][68];
    __shared__ float Bs[32][68];
    const float* wn = ws + OFF_WN;
    float* tn = ws + OFF_TN;
    int t = threadIdx.x;
    int tx = t & 15, ty = t >> 4;
    int bm = blockIdx.x >> 2, bn = blockIdx.x & 3;
    int row0 = bm * 64, col0 = bn * 64;
    int sr = t >> 2;
    int sk = (t & 3) * 8;
    float acc[4][4] = {};
    for (int kt = 0; kt < 8; ++kt) {
        int k0 = kt * 32;
        __syncthreads();
        float4 a0 = loadF4(obj, (row0 + sr) * D_ + k0 + sk, isBF);
        float4 a1 = loadF4(obj, (row0 + sr) * D_ + k0 + sk + 4, isBF);
        float4 b0 = *(const float4*)(wn + (col0 + sr) * D_ + k0 + sk);
        float4 b1 = *(const float4*)(wn + (col0 + sr) * D_ + k0 + sk + 4);
        As[sk+0][sr] = a0.x; As[sk+1][sr] = a0.y; As[sk+2][sr] = a0.z; As[sk+3][sr] = a0.w;
        As[sk+4][sr] = a1.x; As[sk+5][sr] = a1.y; As[sk+6][sr] = a1.z; As[sk+7][sr] = a1.w;
        Bs[sk+0][sr] = b0.x; Bs[sk+1][sr] = b0.y; Bs[sk+2][sr] = b0.z; Bs[sk+3][sr] = b0.w;
        Bs[sk+4][sr] = b1.x; Bs[sk+5][sr] = b1.y; Bs[sk+6][sr] = b1.z; Bs[sk+7][sr] = b1.w;
        __syncthreads();
        #pragma unroll
        for (int k = 0; k < 32; ++k) {
            float4 av = *(const float4*)&As[k][ty * 4];
            float4 bv = *(const float4*)&Bs[k][tx * 4];
            acc[0][0] += av.x * bv.x; acc[0][1] += av.x * bv.y;
            acc[0][2] += av.x * bv.z; acc[0][3] += av.x * bv.w;
            acc[1][0] += av.y * bv.x; acc[1][1] += av.y * bv.y;
            acc[1][2] += av.y * bv.z; acc[1][3] += av.y * bv.w;
            acc[2][0] += av.z * bv.x; acc[2][1] += av.z * bv.y;
            acc[2][2] += av.z * bv.z; acc[2][3] += av.z * bv.w;
            acc[3][0] += av.w * bv.x; acc[3][1] += av.w * bv.y;
            acc[3][2] += av.w * bv.z; acc[3][3] += av.w * bv.w;
        }
    }
    #pragma unroll
    for (int rr = 0; rr < 4; ++rr) {
        float4 o = make_float4(acc[rr][0], acc[rr][1], acc[rr][2], acc[rr][3]);
        *(float4*)&tn[(size_t)(row0 + ty * 4 + rr) * D_ + col0 + tx * 4] = o;
    }
    // fused s1/s2: per-thread partial dot over cols, 16-lane reduce, atomic per row
    float w1v[4], w2v[4];
    #pragma unroll
    for (int c = 0; c < 4; ++c) {
        w1v[c] = ws[OFF_WA + col0 + tx * 4 + c];
        w2v[c] = ws[OFF_WA + D_ + col0 + tx * 4 + c];
    }
    #pragma unroll
    for (int rr = 0; rr < 4; ++rr) {
        float p1 = acc[rr][0]*w1v[0] + acc[rr][1]*w1v[1] + acc[rr][2]*w1v[2] + acc[rr][3]*w1v[3];
        float p2 = acc[rr][0]*w2v[0] + acc[rr][1]*w2v[1] + acc[rr][2]*w2v[2] + acc[rr][3]*w2v[3];
        #pragma unroll
        for (int o = 1; o < 16; o <<= 1) {
            p1 += __shfl_xor(p1, o);
            p2 += __shfl_xor(p2, o);
        }
        if (tx == 0) {
            atomicAdd(&ws[OFF_S1 + row0 + ty * 4 + rr], p1);
            atomicAdd(&ws[OFF_S2 + row0 + ty * 4 + rr], p2);
        }
    }
}

// ---- K3: edge scores, wave per edge (full 131072-wave grid).
//          Masked edges exit before the pred row read (halves pred traffic). ----
__global__ __launch_bounds__(256) void k_scores(const void* pred, const int2* rel,
                                                const void* emask, const void* sim,
                                                float* ws) {
    const int* flags = (const int*)ws;
    int isBF = flags[0], ml = flags[1];
    int gid = blockIdx.x * blockDim.x + threadIdx.x;
    int gw = gid >> 6, lane = gid & 63;
    if (gw >= B_ * E_) return;
    bool m = readMask(emask, gw, ml);      // wave-uniform
    if (!m) {
        if (lane == 0) ws[OFF_SC + gw] = -1e9f;
        return;
    }
    int b = gw >> 13;
    float4 ve4 = *(const float4*)(ws + OFF_VE + lane * 4);
    float dot;
    if (isBF) {
        ushort4 v = *(const ushort4*)((const uint16_t*)pred + (size_t)gw * D_ + lane * 4);
        dot = bf2f(v.x)*ve4.x + bf2f(v.y)*ve4.y + bf2f(v.z)*ve4.z + bf2f(v.w)*ve4.w;
    } else {
        float4 v = *(const float4*)((const float*)pred + (size_t)gw * D_ + lane * 4);
        dot = v.x*ve4.x + v.y*ve4.y + v.z*ve4.z + v.w*ve4.w;
    }
    #pragma unroll
    for (int off = 32; off > 0; off >>= 1) dot += __shfl_xor(dot, off);
    if (lane == 0) {
        int2 sd = rel[gw];
        float s = dot + ws[OFF_S1 + b * N_ + sd.x] + ws[OFF_S2 + b * N_ + sd.y]
                + loadF(sim, gw, isBF) * ws[OFF_WA + 512];
        s = (s > 0.f) ? s : 0.01f * s;                 // leaky_relu
        ws[OFF_SC + gw] = s;
        int bucket = b * N_ + sd.y;
        int slot = atomicAdd((int*)ws + OFF_CNT + bucket, 1);
        if (slot < CAP)
            ((int*)ws)[OFF_REC + bucket * CAP + slot] = sd.x | ((gw & (E_ - 1)) << 16);
    }
}

// ---- K4: per-batch softmax stats (M, 1/S) only ----
__global__ __launch_bounds__(1024) void k_softmax(float* ws) {
    __shared__ float part[16];
    int b = blockIdx.x, t = threadIdx.x, w = t >> 6, lane = t & 63;
    const float* sc = ws + OFF_SC + b * E_;
    float loc[8];
    float mx = -3e38f;
    #pragma unroll
    for (int i = 0; i < 8; ++i) { loc[i] = sc[t + i * 1024]; mx = fmaxf(mx, loc[i]); }
    #pragma unroll
    for (int off = 32; off > 0; off >>= 1) mx = fmaxf(mx, __shfl_xor(mx, off));
    if (lane == 0) part[w] = mx;
    __syncthreads();
    float M = part[0];
    #pragma unroll
    for (int k = 1; k < 16; ++k) M = fmaxf(M, part[k]);
    float sum = 0.f;
    #pragma unroll
    for (int i = 0; i < 8; ++i) sum += __expf(loc[i] - M);
    #pragma unroll
    for (int off = 32; off > 0; off >>= 1) sum += __shfl_xor(sum, off);
    __syncthreads();
    if (lane == 0) part[w] = sum;
    __syncthreads();
    if (t == 0) {
        float S = 0.f;
        #pragma unroll
        for (int k = 0; k < 16; ++k) S += part[k];
        ws[OFF_SM + b * 2]     = M;
        ws[OFF_SM + b * 2 + 1] = 1.f / S;
    }
}

// ---- K5: one WAVE per (batch,node): register accum, on-the-fly softmax weight ----
__global__ __launch_bounds__(256) void k_scatter_ln(const void* nmask, const float* wsc,
                                                    void* out) {
    const float* ws = wsc;
    const int* flags = (const int*)ws;
    int isBF = flags[0], ml = flags[1];
    int t = threadIdx.x, w = t >> 6, lane = t & 63;
    int ng = blockIdx.x * 4 + w;           // (batch,node) bucket, 0..8191
    int b = ng >> 9;
    int cnt = ((const int*)ws)[OFF_CNT + ng];
    if (cnt > CAP) cnt = CAP;
    const int* rec = (const int*)ws + OFF_REC + ng * CAP;
    const float* tn  = ws + OFF_TN + (size_t)b * N_ * D_;
    const float* sc  = ws + OFF_SC + b * E_;
    float M    = ws[OFF_SM + b * 2];
    float invS = ws[OFF_SM + b * 2 + 1];
    float v0 = 0.f, v1 = 0.f, v2 = 0.f, v3 = 0.f;
    for (int i = 0; i < cnt; ++i) {
        int rc = rec[i];
        int src = rc & 0xFFFF;
        float wv = __expf(sc[((unsigned)rc) >> 16] - M) * invS;
        const float* s = tn + (size_t)src * D_;
        v0 += wv * s[lane];
        v1 += wv * s[lane + 64];
        v2 += wv * s[lane + 128];
        v3 += wv * s[lane + 192];
    }
    float mk = readMask(nmask, ng, ml) ? 1.f : 0.f;
    v0 *= mk; v1 *= mk; v2 *= mk; v3 *= mk;
    float sum = v0 + v1 + v2 + v3;
    float sq  = v0*v0 + v1*v1 + v2*v2 + v3*v3;
    #pragma unroll
    for (int o = 32; o > 0; o >>= 1) {
        sum += __shfl_xor(sum, o);
        sq  += __shfl_xor(sq, o);
    }
    float mu  = sum * (1.f / 256.f);
    float var = fmaxf(sq * (1.f / 256.f) - mu * mu, 0.f);
    float rs  = rsqrtf(var + 1e-5f);
    const float* gam = ws + OFF_GAM;
    const float* bet = ws + OFF_BET;
    size_t ro = (size_t)ng * D_;
    float r0 = (v0 - mu) * rs * gam[lane]       + bet[lane];
    float r1 = (v1 - mu) * rs * gam[lane + 64]  + bet[lane + 64];
    float r2 = (v2 - mu) * rs * gam[lane + 128] + bet[lane + 128];
    float r3 = (v3 - mu) * rs * gam[lane + 192] + bet[lane + 192];
    if (isBF) {
        __hip_bfloat16* o = (__hip_bfloat16*)out + ro;
        o[lane]       = __float2bfloat16(r0);
        o[lane + 64]  = __float2bfloat16(r1);
        o[lane + 128] = __float2bfloat16(r2);
        o[lane + 192] = __float2bfloat16(r3);
    } else {
        float* o = (float*)out + ro;
        o[lane] = r0; o[lane + 64] = r1; o[lane + 128] = r2; o[lane + 192] = r3;
    }
}

extern "C" void kernel_launch(void* const* d_in, const int* in_sizes, int n_in,
                              void* d_out, int out_size, void* d_ws, size_t ws_size,
                              hipStream_t stream) {
    (void)in_sizes; (void)n_in; (void)out_size; (void)ws_size;
    const void* obj   = d_in[0];
    const void* pred  = d_in[1];
    const int2* rel   = (const int2*)d_in[2];
    const void* sim   = d_in[3];
    const void* nmask = d_in[4];
    const void* emask = d_in[5];
    const void* wn    = d_in[6];
    const void* we    = d_in[7];
    const void* wa    = d_in[8];
    const void* gam   = d_in[9];
    const void* bet   = d_in[10];
    float* ws = (float*)d_ws;

    k_convert<<<128, 256, 0, stream>>>(obj, emask, wn, we, wa, gam, bet, ws);
    k_vedge<<<32, 256, 0, stream>>>(ws);
    k_nodefc<<<512, 256, 0, stream>>>(obj, ws);
    k_scores<<<(B_ * E_) / 4, 256, 0, stream>>>(pred, rel, emask, sim, ws);
    k_softmax<<<16, 1024, 0, stream>>>(ws);
    k_scatter_ln<<<NBUCKET / 4, 256, 0, stream>>>(nmask, ws, d_out);
}